// Round 3
// baseline (433.197 us; speedup 1.0000x reference)
//
#include <hip/hip_runtime.h>
#include <hip/hip_bf16.h>

// LiZAttention delta-product scan, MI355X — round 3
// p1: 1024 threads (4 waves/SIMD), no clamps (inactive: |h|<<STAB), 4 barriers/chunk,
//     hw-packed bf16 cvt. Emits h per chunk TRANSPOSED (hT[e][d]) bf16 to ws.
// p2: A-frag fp32->bf16 via v_cvt_pk_bf16_f32 (via __float22bfloat162_rn), float4 dots.

#define Dd 128
#define NCH 32
#define YS 16777216  // ys element count; h_final follows in d_out

typedef __attribute__((ext_vector_type(4))) float floatx4;
typedef __attribute__((ext_vector_type(8))) short short8;

__device__ __forceinline__ unsigned int pkbf(float a, float b) {
  union { __hip_bfloat162 h; unsigned int u; } cv;
  cv.h = __float22bfloat162_rn(make_float2(a, b));
  return cv.u;
}

// ---------------- Phase 1: sequential h-scan, h in registers ----------------
__global__ __launch_bounds__(1024) void p1_scan(const float* __restrict__ W,
    const float* __restrict__ U, const float* __restrict__ h0,
    unsigned short* __restrict__ hws, float* __restrict__ out) {
  __shared__ float wpre[NCH * 2 * Dd];   // [n][order][e] 32KB
  __shared__ float upre[NCH * 2 * Dd];   // 32KB
  __shared__ float d10pre[NCH];
  __shared__ float mvp[2 * 8 * Dd];      // [m][g][e] 8KB
  __shared__ float sqb[Dd * 129];        // h' staging for norm (pad 129)
  __shared__ float psum[Dd * 8];         // [d][eq8]
  __shared__ float nrm2[Dd], nrmh[Dd];   // 2/n, n/2

  const int bh = blockIdx.x;
  const int t = threadIdx.x;
  const int e = t & 127, g = t >> 7;     // column e, row group g*16..+15

  // ---- prefetch all W/U c=63 rows (orders 0,1) for all 32 chunks ----
  {
    const float* Wg = W + (size_t)bh * NCH * 16384;
    const float* Ug = U + (size_t)bh * NCH * 16384;
#pragma unroll
    for (int k = 0; k < 2; k++) {
      int idx4 = k * 1024 + t;           // float4 idx, 2048 total
      int n = idx4 >> 6;                 // 64 f4 per chunk (2 rows of 32)
      int rem = idx4 & 63;
      int r = rem >> 5, e4 = (rem & 31) * 4;
      size_t gg = (size_t)n * 16384 + (size_t)(126 + r) * Dd + e4;
      *(float4*)&wpre[idx4 * 4] = *(const float4*)&Wg[gg];
      *(float4*)&upre[idx4 * 4] = *(const float4*)&Ug[gg];
    }
  }
  // ---- stage h0 (row-major) into sqb ----
  {
    const float4* hg = (const float4*)(h0 + (size_t)bh * 16384);
#pragma unroll
    for (int k = 0; k < 4; k++) {
      int idx4 = k * 1024 + t;           // 4096 total
      float4 v = hg[idx4];
      int d = idx4 >> 5, e4 = (idx4 & 31) * 4;
      sqb[d * 129 + e4 + 0] = v.x;
      sqb[d * 129 + e4 + 1] = v.y;
      sqb[d * 129 + e4 + 2] = v.z;
      sqb[d * 129 + e4 + 3] = v.w;
    }
  }
  __syncthreads();
  // ---- d10[n] = w1 . w0 for all chunks ----
  if (t < 512) {
    int n = t >> 4, j = t & 15;
    const float* w0p = &wpre[n * 256 + 8 * j];
    const float* w1p = &wpre[n * 256 + Dd + 8 * j];
    float p = 0.f;
#pragma unroll
    for (int i = 0; i < 8; i++) p += w0p[i] * w1p[i];
    p += __shfl_xor(p, 1, 64);
    p += __shfl_xor(p, 2, 64);
    p += __shfl_xor(p, 4, 64);
    p += __shfl_xor(p, 8, 64);
    if (j == 0) d10pre[n] = p;
  }
  // ---- h column-slice -> registers ----
  float hr[16];
#pragma unroll
  for (int i = 0; i < 16; i++) hr[i] = sqb[(g * 16 + i) * 129 + e];
  __syncthreads();  // d10pre visible; sqb reusable

  unsigned short* hwsb = hws + (size_t)bh * NCH * 16384;
  // ---- chunk 0 state = h0, store transposed bf16 ----
  {
    unsigned int pk[8];
#pragma unroll
    for (int i = 0; i < 8; i++) pk[i] = pkbf(hr[2 * i], hr[2 * i + 1]);
    uint4* dst = (uint4*)(hwsb + (size_t)e * Dd + g * 16);
    dst[0] = make_uint4(pk[0], pk[1], pk[2], pk[3]);
    dst[1] = make_uint4(pk[4], pk[5], pk[6], pk[7]);
  }

  for (int n = 0; n < NCH; n++) {
    // broadcast loads of w0/w1 slice (wave-uniform g)
    floatx4 w0v[4], w1v[4];
#pragma unroll
    for (int i = 0; i < 4; i++) {
      w0v[i] = *(const floatx4*)&wpre[n * 256 + g * 16 + 4 * i];
      w1v[i] = *(const floatx4*)&wpre[n * 256 + Dd + g * 16 + 4 * i];
    }
    // matvec partials over this 16-row slice
    float a0 = 0.f, a1 = 0.f;
#pragma unroll
    for (int i = 0; i < 4; i++)
#pragma unroll
      for (int j = 0; j < 4; j++) {
        float h = hr[4 * i + j];
        a0 += w0v[i][j] * h;
        a1 += w1v[i][j] * h;
      }
    mvp[g * Dd + e] = a0;
    mvp[1024 + g * Dd + e] = a1;
    __syncthreads();                                   // S1
    // uv computed redundantly per-thread (kills a barrier + serial section)
    float uv0, uv1;
    {
      float s0 = 0.f, s1 = 0.f;
#pragma unroll
      for (int gg = 0; gg < 8; gg++) {
        s0 += mvp[gg * Dd + e];
        s1 += mvp[1024 + gg * Dd + e];
      }
      float u0 = upre[n * 256 + e];
      float u1 = upre[n * 256 + Dd + e];
      uv0 = u0 - s0;
      uv1 = u1 - s1 - d10pre[n] * uv0;
    }
    // rank-2 update in registers (no clamp: inactive at these magnitudes)
#pragma unroll
    for (int i = 0; i < 4; i++)
#pragma unroll
      for (int j = 0; j < 4; j++) {
        int ii = 4 * i + j;
        float s = hr[ii] + w0v[i][j] * uv0 + w1v[i][j] * uv1;
        hr[ii] = s;
        sqb[(g * 16 + ii) * 129 + e] = s;
      }
    __syncthreads();                                   // S2
    // row sum-of-squares, rotated index (<=2-way conflicts)
    {
      const int d = t >> 3, eq = t & 7;
      float acc = 0.f;
#pragma unroll
      for (int i = 0; i < 16; i++) {
        int ii = (i + 2 * eq) & 15;
        float v = sqb[d * 129 + eq * 16 + ii];
        acc += v * v;
      }
      psum[d * 8 + eq] = acc;
    }
    __syncthreads();                                   // S3
    if (t < Dd) {
      floatx4 pa = *(const floatx4*)&psum[t * 8];
      floatx4 pb = *(const floatx4*)&psum[t * 8 + 4];
      float nd = sqrtf(pa[0] + pa[1] + pa[2] + pa[3] +
                       pb[0] + pb[1] + pb[2] + pb[3]) + 1e-6f;
      nrm2[t] = 2.0f / nd;
      nrmh[t] = 0.5f * nd;
    }
    __syncthreads();                                   // S4
    // gelu_norm in registers
    floatx4 r2v[4], hnv[4];
#pragma unroll
    for (int i = 0; i < 4; i++) {
      r2v[i] = *(const floatx4*)&nrm2[g * 16 + 4 * i];
      hnv[i] = *(const floatx4*)&nrmh[g * 16 + 4 * i];
    }
#pragma unroll
    for (int i = 0; i < 4; i++)
#pragma unroll
      for (int j = 0; j < 4; j++) {
        int ii = 4 * i + j;
        float x = hr[ii] * r2v[i][j];
        float x2 = x * x;
        float aa = x * fmaf(0.071354816f, x2, 1.59576912f);
        float ex = __expf(-aa);
        float gl = x / (1.0f + ex);
        hr[ii] = hnv[i][j] * gl;
      }
    if (n < NCH - 1) {
      unsigned int pk[8];
#pragma unroll
      for (int i = 0; i < 8; i++) pk[i] = pkbf(hr[2 * i], hr[2 * i + 1]);
      uint4* dst = (uint4*)(hwsb + (size_t)(n + 1) * 16384 + (size_t)e * Dd + g * 16);
      dst[0] = make_uint4(pk[0], pk[1], pk[2], pk[3]);
      dst[1] = make_uint4(pk[4], pk[5], pk[6], pk[7]);
    } else {
      float* ob = out + YS + (size_t)bh * 16384;
#pragma unroll
      for (int i = 0; i < 16; i++) ob[(g * 16 + i) * Dd + e] = hr[i];
    }
  }
}

// ---------------- Phase 2: per-tile outputs via MFMA ----------------
// wave w (of 8): pair p=w>>2 (0:{Q0,W0}, 1:{Q1,W1}), e-quarter eq=w&3
// 16x16x32 bf16 MFMA: A[m=lane&15][k=8*(lane>>4)+i]; B[k][n=lane&15];
//                     C/D: row=4*(lane>>4)+reg, col=lane&15   [m89/m91]
__global__ __launch_bounds__(512) void p2_out(const float* __restrict__ Q,
    const float* __restrict__ W, const float* __restrict__ U,
    const unsigned short* __restrict__ hws, float* __restrict__ out) {
  __shared__ unsigned short hT[Dd * 136];  // transposed h, pad 136 (16B-aligned rows)
  __shared__ float d10s[64], dq1s[64];
  __shared__ float dps[512];

  const int bid = blockIdx.x;
  const int n = bid & 31, bh = bid >> 5;
  const size_t base = (size_t)(bh * NCH + n) * 16384;
  const float* Qb = Q + base;
  const float* Wb = W + base;
  const float* Ub = U + base;
  float* Ob = out + base;
  const int t = threadIdx.x;

  // stage hT (global e-major, stride 128) -> LDS stride 136
  {
    const uint4* src = (const uint4*)(hws + base);
#pragma unroll
    for (int i = 0; i < 4; i++) {
      int idx = t + i * 512;             // uint4 idx, 2048 total
      uint4 v = src[idx];
      int e = idx >> 4, j = idx & 15;
      *(uint4*)&hT[e * 136 + j * 8] = v;
    }
  }
  // per-c dots: d10[c]=w1.w0, dq1[c]=q1.w0  (float4 loads)
  {
    int which = t >> 8, tt = t & 255;
    int c = tt >> 2, part = tt & 3;
    const float4* ar = (const float4*)((which ? Qb : Wb) + (2 * c + 1) * Dd + part * 32);
    const float4* w0r = (const float4*)(Wb + (2 * c) * Dd + part * 32);
    float s = 0.f;
#pragma unroll
    for (int i = 0; i < 8; i++) {
      float4 a = ar[i], b = w0r[i];
      s += a.x * b.x + a.y * b.y + a.z * b.z + a.w * b.w;
    }
    dps[which * 256 + tt] = s;
  }
  __syncthreads();
  if (t < 128) {
    int which = t >> 6, c = t & 63;
    const float* p = dps + which * 256 + c * 4;
    float s = p[0] + p[1] + p[2] + p[3];
    (which ? dq1s : d10s)[c] = s;
  }

  const int wv = t >> 6, l = t & 63;
  const int pr = wv >> 2, eq = wv & 3;
  const int lm = l & 15, lq = l >> 4;

  floatx4 acc[2][4][2];  // [mat 0=Q_p,1=W_p][ctile][etile]
#pragma unroll
  for (int m = 0; m < 2; m++)
#pragma unroll
    for (int ci = 0; ci < 4; ci++)
#pragma unroll
      for (int j = 0; j < 2; j++) acc[m][ci][j] = (floatx4){0.f, 0.f, 0.f, 0.f};

  for (int kc = 0; kc < 4; kc++) {
    const int k0 = kc * 32;
    short8 bfr[2];
#pragma unroll
    for (int j = 0; j < 2; j++) {
      int ee = (2 * eq + j) * 16 + lm;
      bfr[j] = *(const short8*)&hT[ee * 136 + k0 + 8 * lq];  // one ds_read_b128
    }
#pragma unroll
    for (int m = 0; m < 2; m++) {
      const float* X = m ? Wb : Qb;
#pragma unroll
      for (int ci = 0; ci < 4; ci++) {
        int c = ci * 16 + lm;
        const float* row = X + (size_t)(2 * c + pr) * Dd + k0 + 8 * lq;
        float4 f0 = ((const float4*)row)[0];
        float4 f1 = ((const float4*)row)[1];
        union { short8 v; __hip_bfloat162 b2[4]; } af;
        af.b2[0] = __float22bfloat162_rn(make_float2(f0.x, f0.y));
        af.b2[1] = __float22bfloat162_rn(make_float2(f0.z, f0.w));
        af.b2[2] = __float22bfloat162_rn(make_float2(f1.x, f1.y));
        af.b2[3] = __float22bfloat162_rn(make_float2(f1.z, f1.w));
        acc[m][ci][0] = __builtin_amdgcn_mfma_f32_16x16x32_bf16(af.v, bfr[0], acc[m][ci][0], 0, 0, 0);
        acc[m][ci][1] = __builtin_amdgcn_mfma_f32_16x16x32_bf16(af.v, bfr[1], acc[m][ci][1], 0, 0, 0);
      }
    }
  }
  __syncthreads();  // matmuls done; hT LDS dead -> alias as uv0 (fp32 64x128)
  float* uv0s = (float*)hT;

  if (pr == 0) {
#pragma unroll
    for (int ci = 0; ci < 4; ci++)
#pragma unroll
      for (int j = 0; j < 2; j++) {
        int ee = (2 * eq + j) * 16 + lm;
#pragma unroll
        for (int r = 0; r < 4; r++) {
          int c = ci * 16 + lq * 4 + r;
          float T0 = acc[1][ci][j][r];   // w0^T h
          float Q0h = acc[0][ci][j][r];  // q0^T h
          float u0 = Ub[(2 * c) * Dd + ee];
          float q0 = Qb[(2 * c) * Dd + ee];
          float uv0 = u0 - T0;
          uv0s[c * Dd + ee] = uv0;
          Ob[(2 * c) * Dd + ee] = q0 * uv0 + Q0h;
        }
      }
  }
  __syncthreads();
  if (pr == 1) {
#pragma unroll
    for (int ci = 0; ci < 4; ci++)
#pragma unroll
      for (int j = 0; j < 2; j++) {
        int ee = (2 * eq + j) * 16 + lm;
#pragma unroll
        for (int r = 0; r < 4; r++) {
          int c = ci * 16 + lq * 4 + r;
          float T1 = acc[1][ci][j][r];   // w1^T h
          float Q1h = acc[0][ci][j][r];  // q1^T h
          float u1 = Ub[(2 * c + 1) * Dd + ee];
          float q1 = Qb[(2 * c + 1) * Dd + ee];
          float uv0 = uv0s[c * Dd + ee];
          float uv1 = u1 - T1 - d10s[c] * uv0;
          Ob[(2 * c + 1) * Dd + ee] = q1 * uv1 + Q1h + dq1s[c] * uv0;
        }
      }
  }
}

extern "C" void kernel_launch(void* const* d_in, const int* in_sizes, int n_in,
                              void* d_out, int out_size, void* d_ws, size_t ws_size,
                              hipStream_t stream) {
  const float* Q = (const float*)d_in[0];
  const float* W = (const float*)d_in[1];
  const float* U = (const float*)d_in[2];
  const float* h0 = (const float*)d_in[3];
  float* out = (float*)d_out;
  unsigned short* hws = (unsigned short*)d_ws;  // 32 MiB, transposed [e][d] bf16

  p1_scan<<<32, 1024, 0, stream>>>(W, U, h0, hws, out);
  p2_out<<<1024, 512, 0, stream>>>(Q, W, U, hws, out);
}